// Round 11
// baseline (179.224 us; speedup 1.0000x reference)
//
#include <hip/hip_runtime.h>
#include <stdint.h>
#include <stddef.h>

#define C_TOTAL   256
#define NBINS     49
#define NSAMP     196                  // 14 x 14 sample grid
#define TILE_D    1152                 // dwords per channel tile (worst padded footprint ~1090)
#define SD_STRIDE 16                   // ints per roi scalar descriptor
#define BLOB_DW   (NSAMP * 4)          // 784 dwords: compact 16B/sample descriptors
#define SORTN     1024
#define NBLK      8192                 // main-kernel blocks
#define WPB       8                    // waves per block (512 threads)

// ws layout (dwords):
//   [0, K*SD_STRIDE)                : sd per original roi k (sd[7]=k)
//   blobBase = K*SD_STRIDE          : K*BLOB_DW compact sample blobs (by k)
//   kbase = blobBase + K*BLOB_DW    : SORTN sort keys
//   sbase = kbase + SORTN           : K*SD_STRIDE rank-ordered sd

// ---------------------------------------------------------------------------
// Pre-kernel A: one block per roi. Scalar staging geometry + sort key +
// compact sample descriptors {c00, pack(dx|rowDelta|invalid), lx, ly}.
// ---------------------------------------------------------------------------
__global__ __launch_bounds__(256)
void roi_desc_kernel(const float* __restrict__ rois, int* __restrict__ ws_i,
                     int blobBase, int kbase)
{
    const int k   = blockIdx.x;
    const int tid = threadIdx.x;

    const float bf  = rois[k * 5 + 0];
    const float rx1 = rois[k * 5 + 1];
    const float ry1 = rois[k * 5 + 2];
    const float rx2 = rois[k * 5 + 3];
    const float ry2 = rois[k * 5 + 4];
    const int   b   = (int)bf;

    const float scale = sqrtf((rx2 - rx1 + 1.0f) * (ry2 - ry1 + 1.0f));
    int lvl = (int)floorf(log2f(scale / 56.0f + 1e-6f));
    lvl = lvl < 0 ? 0 : (lvl > 3 ? 3 : lvl);

    int H, W;
    if      (lvl == 0) { H = 200; W = 336; }
    else if (lvl == 1) { H = 100; W = 168; }
    else if (lvl == 2) { H =  50; W =  84; }
    else               { H =  25; W =  42; }

    const float ss  = 1.0f / (float)(4 << lvl);
    const float x1s = rx1 * ss, y1s = ry1 * ss;
    const float x2s = rx2 * ss, y2s = ry2 * ss;
    const float roi_w = fmaxf(x2s - x1s, 1.0f);
    const float roi_h = fmaxf(y2s - y1s, 1.0f);
    const float bw = roi_w * (1.0f / 7.0f);
    const float bh = roi_h * (1.0f / 7.0f);

    const float Hm1 = (float)(H - 1), Wm1 = (float)(W - 1);
    const int ty0 = (int)floorf(fminf(fmaxf(y1s + 0.25f * bh, 0.0f), Hm1));
    const int tx0 = (int)floorf(fminf(fmaxf(x1s + 0.25f * bw, 0.0f), Wm1));
    const int ty1 = min((int)floorf(fminf(fmaxf(y1s + 6.75f * bh, 0.0f), Hm1)) + 1, H - 1);
    const int tx1 = min((int)floorf(fminf(fmaxf(x1s + 6.75f * bw, 0.0f), Wm1)) + 1, W - 1);
    const int fh = ty1 - ty0 + 1;
    const int fw = tx1 - tx0 + 1;

    int cpr = (fw + (tx0 & 3) + 3) >> 2;
    if (cpr > (W >> 2)) cpr = W >> 2;
    const bool use16 = (lvl < 3) && (fh * cpr <= TILE_D / 4);

    int rb, rowStride, chunks;
    if (use16) {
        rb = tx0 & ~3;
        if (rb + 4 * cpr > W) rb = W - 4 * cpr;   // stays 4-aligned (W%4==0 for lvl<3)
        rowStride = 4 * cpr;
        chunks = fh * cpr;                        // dwordx4 units
        if (chunks > TILE_D / 4) chunks = TILE_D / 4;
    } else {
        rb = tx0;
        rowStride = fw;
        chunks = fh * fw;                         // dword units
        if (chunks > TILE_D) chunks = TILE_D;
    }
    const uint32_t d = use16 ? (uint32_t)cpr : (uint32_t)fw;
    const uint32_t M = (1u << 22) / d + 1u;       // exact for idx<1920, d<=336
    const int dW = W - rowStride;

    if (tid == 0) {
        int* sd = ws_i + k * SD_STRIDE;
        sd[0] = lvl;
        sd[1] = use16 ? 1 : 0;
        sd[2] = b * C_TOTAL * H * W + ty0 * W + rb;
        sd[3] = chunks;
        sd[4] = (int)M;
        sd[5] = dW;
        sd[6] = H * W;
        sd[7] = k;
        // sort key: level major, batch, Morton(center), id in low bits
        const float cx = 0.5f * (rx1 + rx2);
        const float cy = 0.5f * (ry1 + ry2);
        int qx = (int)(cx * (64.0f / 1344.0f));
        int qy = (int)(cy * (64.0f / 800.0f));
        qx = qx < 0 ? 0 : (qx > 63 ? 63 : qx);
        qy = qy < 0 ? 0 : (qy > 63 ? 63 : qy);
        unsigned m = 0;
#pragma unroll
        for (int j = 0; j < 6; ++j)
            m |= (((unsigned)(qx >> j) & 1u) << (2 * j)) |
                 (((unsigned)(qy >> j) & 1u) << (2 * j + 1));
        ws_i[kbase + k] = (int)(((unsigned)lvl << 23) | ((unsigned)b << 22)
                                | (m << 10) | (unsigned)k);
    }

    if (tid < NSAMP) {
        const int iy = tid / 14;
        const int ix = tid - iy * 14;
        const float yy = y1s + ((float)iy * 0.5f + 0.25f) * bh;
        const float xx = x1s + ((float)ix * 0.5f + 0.25f) * bw;
        const bool valid = (yy > -1.0f) && (yy < (float)H) && (xx > -1.0f) && (xx < (float)W);
        const float yc  = fminf(fmaxf(yy, 0.0f), Hm1);
        const float xc  = fminf(fmaxf(xx, 0.0f), Wm1);
        const float y0f = floorf(yc);
        const float x0f = floorf(xc);
        const float ly = yc - y0f, lx = xc - x0f;
        const int y0  = (int)y0f, x0 = (int)x0f;
        const int y1i = min(y0 + 1, H - 1);
        const int x1i = min(x0 + 1, W - 1);
        const int r0 = (y0  - ty0) * rowStride - rb;
        const int rd = (y1i - y0) * rowStride;        // 0 or rowStride
        const int dx = x1i - x0;                      // 0 or 1
        const int pack = (valid ? 0 : (int)0x80000000) | (rd << 1) | dx;
        int4* blob = (int4*)(ws_i + blobBase + (size_t)k * BLOB_DW);
        blob[tid] = make_int4(r0 + x0, pack,
                              __float_as_int(lx), __float_as_int(ly));
    }
}

// ---------------------------------------------------------------------------
// Pre-kernel B: single block. Bitonic-sort keys, gather sd into rank order.
// ---------------------------------------------------------------------------
__global__ __launch_bounds__(256)
void roi_sort_kernel(int* __restrict__ ws_i, int K, int kbase, int sbase)
{
    __shared__ unsigned skey[SORTN];
    const int tid = threadIdx.x;

    const bool do_sort = (K <= SORTN);
    if (do_sort) {
        for (int i = tid; i < SORTN; i += 256)
            skey[i] = (i < K) ? (unsigned)ws_i[kbase + i] : 0xFFFFFFFFu;
        __syncthreads();
        for (unsigned size = 2; size <= SORTN; size <<= 1) {
            for (unsigned stride = size >> 1; stride; stride >>= 1) {
                for (int i = tid; i < SORTN; i += 256) {
                    const unsigned p = (unsigned)i ^ stride;
                    if (p > (unsigned)i) {
                        const bool up = ((i & size) == 0);
                        const unsigned a = skey[i], b = skey[p];
                        if ((a > b) == up) { skey[i] = b; skey[p] = a; }
                    }
                }
                __syncthreads();
            }
        }
    }
    for (int i = tid; i < K * SD_STRIDE; i += 256) {
        const int rank = i >> 4, j = i & 15;
        const int k = do_sort ? (int)(skey[rank] & 1023u) : rank;
        ws_i[sbase + i] = ws_i[k * SD_STRIDE + j];
    }
}

// ---------------------------------------------------------------------------
// Main kernel: BARRIER-FREE. Each wave independently processes tasks
// (roi-rank, channel) in a grid-stride loop: per-lane desc loads (registers),
// private LDS tile slice via DMA, per-wave vmcnt(0), compute, store.
// Next task's scalar descriptor is prefetched (s_load) before the wait.
// ---------------------------------------------------------------------------
__global__ __launch_bounds__(512, 8)
void roi_align_main(const float* __restrict__ f0,
                    const float* __restrict__ f1,
                    const float* __restrict__ f2,
                    const float* __restrict__ f3,
                    const int* __restrict__ ws_i,
                    float* __restrict__ out,
                    int blobBase, int sbase, int K)
{
    __shared__ __align__(16) float s_tile[WPB * TILE_D];   // 36864 B -> 4 blk/CU

    const int tid  = threadIdx.x;
    const int wv   = tid >> 6;       // 0..7
    const int lane = tid & 63;
    const int Wid  = blockIdx.x * WPB + wv;     // global wave id
    const int totalW = NBLK * WPB;
    const int nTask  = K * C_TOTAL;

    const int oy = lane / 7;
    const int ox = lane - oy * 7;
    const int sbin = (lane < NBINS) ? (oy * 28 + ox * 2) : 0;   // clamp idle lanes

    float* dst = s_tile + wv * TILE_D;

    int T = Wid;
    if (T >= nTask) return;                      // wave-uniform; no barriers anywhere

    // scalar descriptor for first task
    int rank = T % K;
    const int* sp = ws_i + sbase + rank * SD_STRIDE;
    int lvl = sp[0], use16 = sp[1], srcBase = sp[2], chunks = sp[3];
    uint32_t M = (uint32_t)sp[4];
    int dW = sp[5], HW = sp[6], k = sp[7];

    while (true) {
        const int c = T / K;
        const float* feat = (lvl == 0) ? f0 : (lvl == 1) ? f1 : (lvl == 2) ? f2 : f3;

        // ---- per-lane tap descriptors straight to registers (issue first) ----
        const int4* dg = (const int4*)(ws_i + blobBase + (size_t)k * BLOB_DW);
        const int4 d0 = dg[sbin];
        const int4 d1 = dg[sbin + 1];
        const int4 d2 = dg[sbin + 14];
        const int4 d3 = dg[sbin + 15];

        // ---- tile staging into private slice, async DMA, overlap tail ----
        {
            const float* src = feat + srcBase + (size_t)c * (size_t)HW;
            if (use16) {
                for (int start = 0; start < chunks; start += 64) {
                    int s = (start + 64 > chunks) ? max(chunks - 64, 0) : start;
                    int idx = s + lane;
                    if (idx >= chunks) idx = chunks - 1;     // only when chunks<64
                    const int fy  = (int)(((uint32_t)idx * M) >> 22);
                    const int off = (idx << 2) + fy * dW;
                    __builtin_amdgcn_global_load_lds(
                        (const __attribute__((address_space(1))) uint32_t*)(src + off),
                        (__attribute__((address_space(3))) uint32_t*)(dst + (s << 2)),
                        16, 0, 0);
                }
            } else {
                for (int start = 0; start < chunks; start += 64) {
                    int s = (start + 64 > chunks) ? max(chunks - 64, 0) : start;
                    int idx = s + lane;
                    if (idx >= chunks) idx = chunks - 1;
                    const int fy  = (int)(((uint32_t)idx * M) >> 22);
                    const int off = idx + fy * dW;
                    __builtin_amdgcn_global_load_lds(
                        (const __attribute__((address_space(1))) uint32_t*)(src + off),
                        (__attribute__((address_space(3))) uint32_t*)(dst + s),
                        4, 0, 0);
                }
            }
        }

        // ---- prefetch next task's scalar descriptor (s_load; lgkm counter,
        //      completes during the vmcnt wait below) ----
        const int Tn = T + totalW;
        const bool more = (Tn < nTask);
        int lvl2 = 0, use162 = 0, srcBase2 = 0, chunks2 = 0, dW2 = 0, HW2 = 0, k2 = 0;
        uint32_t M2 = 0;
        if (more) {
            const int r2 = Tn % K;
            const int* sq = ws_i + sbase + r2 * SD_STRIDE;
            lvl2 = sq[0]; use162 = sq[1]; srcBase2 = sq[2]; chunks2 = sq[3];
            M2 = (uint32_t)sq[4]; dW2 = sq[5]; HW2 = sq[6]; k2 = sq[7];
        }

        asm volatile("s_waitcnt vmcnt(0)" ::: "memory");   // per-wave drain; NO barrier

        // ---- gather-FMA tap loop: one bin per lane ----
        if (lane < NBINS) {
            const float* t = dst;
            float acc = 0.0f;
#pragma unroll
            for (int j = 0; j < 4; ++j) {
                const int4 dcp = (j == 0) ? d0 : (j == 1) ? d1 : (j == 2) ? d2 : d3;
                const float lx = __int_as_float(dcp.z);
                const float ly = __int_as_float(dcp.w);
                const float hx = 1.0f - lx, hy = 1.0f - ly;
                const float v  = (dcp.y < 0) ? 0.0f : 0.25f;
                const int dx  = dcp.y & 1;
                const int rd  = (dcp.y >> 1) & 0xFFFF;
                const int c00 = dcp.x;
                acc += (hy * hx * v) * t[c00]
                     + (hy * lx * v) * t[c00 + dx]
                     + (ly * hx * v) * t[c00 + rd]
                     + (ly * lx * v) * t[c00 + rd + dx];
            }
            out[((size_t)k * C_TOTAL + c) * NBINS + lane] = acc;
        }

        if (!more) break;
        T = Tn;
        lvl = lvl2; use16 = use162; srcBase = srcBase2; chunks = chunks2;
        M = M2; dW = dW2; HW = HW2; k = k2;
    }
}

extern "C" void kernel_launch(void* const* d_in, const int* in_sizes, int n_in,
                              void* d_out, int out_size, void* d_ws, size_t ws_size,
                              hipStream_t stream) {
    const float* f0   = (const float*)d_in[0];
    const float* f1   = (const float*)d_in[1];
    const float* f2   = (const float*)d_in[2];
    const float* f3   = (const float*)d_in[3];
    const float* rois = (const float*)d_in[4];
    float* out = (float*)d_out;
    int*   ws  = (int*)d_ws;

    const int K = in_sizes[4] / 5;
    const int blobBase = K * SD_STRIDE;
    const int kbase    = blobBase + K * BLOB_DW;
    const int sbase    = kbase + SORTN;

    roi_desc_kernel<<<K, 256, 0, stream>>>(rois, ws, blobBase, kbase);
    roi_sort_kernel<<<1, 256, 0, stream>>>(ws, K, kbase, sbase);

    roi_align_main<<<NBLK, 512, 0, stream>>>(f0, f1, f2, f3, ws, out,
                                             blobBase, sbase, K);
}

// Round 12
// 131.946 us; speedup vs baseline: 1.3583x; 1.3583x over previous
//
#include <hip/hip_runtime.h>
#include <hip/hip_fp16.h>
#include <stdint.h>
#include <stddef.h>

#define C_TOTAL   256
#define CPG       8                    // channels per block (one wave each)
#define NGROUPS   (C_TOTAL / CPG)      // 32
#define NBINS     49
#define NSAMP     196                  // 14 x 14 sample grid
#define TILE_D    1152                 // dwords per channel tile (worst padded footprint ~1090)
#define SD_STRIDE 16                   // ints per roi scalar descriptor
#define BLOB_DW   (NSAMP * 2)          // 392 dwords: packed 8B/sample descriptors
#define SORTN     1024

// ws layout (dwords):
//   [0, K*SD_STRIDE)                : sd per original roi k (sd[7]=k)
//   blobBase = K*SD_STRIDE          : K*BLOB_DW packed sample blobs (by k)
//   kbase = blobBase + K*BLOB_DW    : SORTN sort keys
//   sbase = kbase + SORTN           : K*SD_STRIDE rank-ordered sd

// packed sample: .x = c00 | rd<<11 | dx<<22 | invalid<<31 ; .y = half2(lx, ly)

// ---------------------------------------------------------------------------
// Pre-kernel A: one block per roi. Scalar staging geometry + sort key +
// packed sample descriptors.
// ---------------------------------------------------------------------------
__global__ __launch_bounds__(256)
void roi_desc_kernel(const float* __restrict__ rois, int* __restrict__ ws_i,
                     int blobBase, int kbase)
{
    const int k   = blockIdx.x;
    const int tid = threadIdx.x;

    const float bf  = rois[k * 5 + 0];
    const float rx1 = rois[k * 5 + 1];
    const float ry1 = rois[k * 5 + 2];
    const float rx2 = rois[k * 5 + 3];
    const float ry2 = rois[k * 5 + 4];
    const int   b   = (int)bf;

    const float scale = sqrtf((rx2 - rx1 + 1.0f) * (ry2 - ry1 + 1.0f));
    int lvl = (int)floorf(log2f(scale / 56.0f + 1e-6f));
    lvl = lvl < 0 ? 0 : (lvl > 3 ? 3 : lvl);

    int H, W;
    if      (lvl == 0) { H = 200; W = 336; }
    else if (lvl == 1) { H = 100; W = 168; }
    else if (lvl == 2) { H =  50; W =  84; }
    else               { H =  25; W =  42; }

    const float ss  = 1.0f / (float)(4 << lvl);
    const float x1s = rx1 * ss, y1s = ry1 * ss;
    const float x2s = rx2 * ss, y2s = ry2 * ss;
    const float roi_w = fmaxf(x2s - x1s, 1.0f);
    const float roi_h = fmaxf(y2s - y1s, 1.0f);
    const float bw = roi_w * (1.0f / 7.0f);
    const float bh = roi_h * (1.0f / 7.0f);

    const float Hm1 = (float)(H - 1), Wm1 = (float)(W - 1);
    const int ty0 = (int)floorf(fminf(fmaxf(y1s + 0.25f * bh, 0.0f), Hm1));
    const int tx0 = (int)floorf(fminf(fmaxf(x1s + 0.25f * bw, 0.0f), Wm1));
    const int ty1 = min((int)floorf(fminf(fmaxf(y1s + 6.75f * bh, 0.0f), Hm1)) + 1, H - 1);
    const int tx1 = min((int)floorf(fminf(fmaxf(x1s + 6.75f * bw, 0.0f), Wm1)) + 1, W - 1);
    const int fh = ty1 - ty0 + 1;
    const int fw = tx1 - tx0 + 1;

    int cpr = (fw + (tx0 & 3) + 3) >> 2;
    if (cpr > (W >> 2)) cpr = W >> 2;
    const bool use16 = (lvl < 3) && (fh * cpr <= TILE_D / 4);

    int rb, rowStride, chunks;
    if (use16) {
        rb = tx0 & ~3;
        if (rb + 4 * cpr > W) rb = W - 4 * cpr;   // stays 4-aligned (W%4==0 for lvl<3)
        rowStride = 4 * cpr;
        chunks = fh * cpr;                        // dwordx4 units
        if (chunks > TILE_D / 4) chunks = TILE_D / 4;
    } else {
        rb = tx0;
        rowStride = fw;
        chunks = fh * fw;                         // dword units
        if (chunks > TILE_D) chunks = TILE_D;
    }
    const uint32_t d = use16 ? (uint32_t)cpr : (uint32_t)fw;
    const uint32_t M = (1u << 22) / d + 1u;       // exact for idx<1920, d<=336
    const int dW = W - rowStride;

    if (tid == 0) {
        int* sd = ws_i + k * SD_STRIDE;
        sd[0] = lvl;
        sd[1] = use16 ? 1 : 0;
        sd[2] = b * C_TOTAL * H * W + ty0 * W + rb;
        sd[3] = chunks;
        sd[4] = (int)M;
        sd[5] = dW;
        sd[6] = H * W;
        sd[7] = k;
        // sort key: level major, batch, Morton(center), id in low bits
        const float cx = 0.5f * (rx1 + rx2);
        const float cy = 0.5f * (ry1 + ry2);
        int qx = (int)(cx * (64.0f / 1344.0f));
        int qy = (int)(cy * (64.0f / 800.0f));
        qx = qx < 0 ? 0 : (qx > 63 ? 63 : qx);
        qy = qy < 0 ? 0 : (qy > 63 ? 63 : qy);
        unsigned m = 0;
#pragma unroll
        for (int j = 0; j < 6; ++j)
            m |= (((unsigned)(qx >> j) & 1u) << (2 * j)) |
                 (((unsigned)(qy >> j) & 1u) << (2 * j + 1));
        ws_i[kbase + k] = (int)(((unsigned)lvl << 23) | ((unsigned)b << 22)
                                | (m << 10) | (unsigned)k);
    }

    if (tid < NSAMP) {
        const int iy = tid / 14;
        const int ix = tid - iy * 14;
        const float yy = y1s + ((float)iy * 0.5f + 0.25f) * bh;
        const float xx = x1s + ((float)ix * 0.5f + 0.25f) * bw;
        const bool valid = (yy > -1.0f) && (yy < (float)H) && (xx > -1.0f) && (xx < (float)W);
        const float yc  = fminf(fmaxf(yy, 0.0f), Hm1);
        const float xc  = fminf(fmaxf(xx, 0.0f), Wm1);
        const float y0f = floorf(yc);
        const float x0f = floorf(xc);
        const float ly = yc - y0f, lx = xc - x0f;
        const int y0  = (int)y0f, x0 = (int)x0f;
        const int y1i = min(y0 + 1, H - 1);
        const int x1i = min(x0 + 1, W - 1);
        const int r0 = (y0  - ty0) * rowStride - rb;
        const int rd = (y1i - y0) * rowStride;        // 0 or rowStride (<2048)
        const int dx = x1i - x0;                      // 0 or 1
        const int c00 = r0 + x0;                      // 0..1151 (<2048)
        const int pk = c00 | (rd << 11) | (dx << 22) | (valid ? 0 : (int)0x80000000);
        const __half2 l2 = __floats2half2_rn(lx, ly);
        uint2* blob = (uint2*)(ws_i + blobBase + (size_t)k * BLOB_DW);
        uint2 v; v.x = (unsigned)pk; v.y = *(const unsigned*)&l2;
        blob[tid] = v;
    }
}

// ---------------------------------------------------------------------------
// Pre-kernel B: single block. Bitonic-sort keys, gather sd into rank order.
// ---------------------------------------------------------------------------
__global__ __launch_bounds__(256)
void roi_sort_kernel(int* __restrict__ ws_i, int K, int kbase, int sbase)
{
    __shared__ unsigned skey[SORTN];
    const int tid = threadIdx.x;

    const bool do_sort = (K <= SORTN);
    if (do_sort) {
        for (int i = tid; i < SORTN; i += 256)
            skey[i] = (i < K) ? (unsigned)ws_i[kbase + i] : 0xFFFFFFFFu;
        __syncthreads();
        for (unsigned size = 2; size <= SORTN; size <<= 1) {
            for (unsigned stride = size >> 1; stride; stride >>= 1) {
                for (int i = tid; i < SORTN; i += 256) {
                    const unsigned p = (unsigned)i ^ stride;
                    if (p > (unsigned)i) {
                        const bool up = ((i & size) == 0);
                        const unsigned a = skey[i], b = skey[p];
                        if ((a > b) == up) { skey[i] = b; skey[p] = a; }
                    }
                }
                __syncthreads();
            }
        }
    }
    for (int i = tid; i < K * SD_STRIDE; i += 256) {
        const int rank = i >> 4, j = i & 15;
        const int k = do_sort ? (int)(skey[rank] & 1023u) : rank;
        ws_i[sbase + i] = ws_i[k * SD_STRIDE + j];
    }
}

// ---------------------------------------------------------------------------
// Main kernel: R10 skeleton. Changes: (1) packed 8B/sample desc -> 2 DMA
// insts on waves 0-1; (2) masked tile tail (guarded) instead of overlap.
// ---------------------------------------------------------------------------
__global__ __launch_bounds__(512, 8)
void roi_align_main(const float* __restrict__ f0,
                    const float* __restrict__ f1,
                    const float* __restrict__ f2,
                    const float* __restrict__ f3,
                    const int* __restrict__ ws_i,
                    float* __restrict__ out,
                    int blobBase, int sbase)
{
    __shared__ __align__(16) float s_tile[CPG * TILE_D];   // 36864 B
    __shared__ __align__(16) float s_desc[BLOB_DW];        //  1568 B -> 38432 B, 4 blk/CU

    const int rank = blockIdx.y;
    const int g    = blockIdx.x;
    const int tid  = threadIdx.x;
    const int wv   = tid >> 6;       // 0..7
    const int lane = tid & 63;

    const int* sd = ws_i + sbase + rank * SD_STRIDE;
    const int lvl     = sd[0];
    const int use16   = sd[1];
    const int srcBase = sd[2];
    const int chunks  = sd[3];
    const uint32_t M  = (uint32_t)sd[4];
    const int dW      = sd[5];
    const int HW      = sd[6];
    const int k       = sd[7];

    const float* feat = (lvl == 0) ? f0 : (lvl == 1) ? f1 : (lvl == 2) ? f2 : f3;

    // ---- descriptor blob: 98 16B-chunks, 2 insts on waves 0-1 ----
    // i0 = 0, 34: [0,64) + [34,98) covers [0,98)
    if (wv < 2) {
        const int i0 = wv ? 34 : 0;
        const float* bsrc = (const float*)(ws_i + blobBase + (size_t)k * BLOB_DW);
        __builtin_amdgcn_global_load_lds(
            (const __attribute__((address_space(1))) uint32_t*)(bsrc + ((i0 + lane) << 2)),
            (__attribute__((address_space(3))) uint32_t*)(s_desc + (i0 << 2)),
            16, 0, 0);
    }

    // ---- tile staging: one wave per channel, async DMA ----
    {
        const int c = g * CPG + wv;
        const float* src = feat + srcBase + (size_t)c * (size_t)HW;
        float* dst = s_tile + wv * TILE_D;
        const int nfull = chunks & ~63;
        const int rem   = chunks - nfull;
        if (use16) {
            for (int s = 0; s < nfull; s += 64) {
                const int idx = s + lane;
                const int fy  = (int)(((uint32_t)idx * M) >> 22);
                const int off = (idx << 2) + fy * dW;
                __builtin_amdgcn_global_load_lds(
                    (const __attribute__((address_space(1))) uint32_t*)(src + off),
                    (__attribute__((address_space(3))) uint32_t*)(dst + (s << 2)),
                    16, 0, 0);
            }
            if (rem) {
                if (nfull <= TILE_D / 4 - 64) {
                    // masked tail: only lanes < rem issue; writes confined to slice
                    if (lane < rem) {
                        const int idx = nfull + lane;
                        const int fy  = (int)(((uint32_t)idx * M) >> 22);
                        const int off = (idx << 2) + fy * dW;
                        __builtin_amdgcn_global_load_lds(
                            (const __attribute__((address_space(1))) uint32_t*)(src + off),
                            (__attribute__((address_space(3))) uint32_t*)(dst + (nfull << 2)),
                            16, 0, 0);
                    }
                } else {
                    // overlap tail (nfull >= 224 => chunks >= 225 > 64): all in-bounds
                    const int s2  = chunks - 64;
                    const int idx = s2 + lane;
                    const int fy  = (int)(((uint32_t)idx * M) >> 22);
                    const int off = (idx << 2) + fy * dW;
                    __builtin_amdgcn_global_load_lds(
                        (const __attribute__((address_space(1))) uint32_t*)(src + off),
                        (__attribute__((address_space(3))) uint32_t*)(dst + (s2 << 2)),
                        16, 0, 0);
                }
            }
        } else {
            for (int s = 0; s < nfull; s += 64) {
                const int idx = s + lane;
                const int fy  = (int)(((uint32_t)idx * M) >> 22);
                const int off = idx + fy * dW;
                __builtin_amdgcn_global_load_lds(
                    (const __attribute__((address_space(1))) uint32_t*)(src + off),
                    (__attribute__((address_space(3))) uint32_t*)(dst + s),
                    4, 0, 0);
            }
            if (rem) {
                // always safe for dword units: nfull+64 <= 1152 when rem>0
                if (lane < rem) {
                    const int idx = nfull + lane;
                    const int fy  = (int)(((uint32_t)idx * M) >> 22);
                    const int off = idx + fy * dW;
                    __builtin_amdgcn_global_load_lds(
                        (const __attribute__((address_space(1))) uint32_t*)(src + off),
                        (__attribute__((address_space(3))) uint32_t*)(dst + nfull),
                        4, 0, 0);
                }
            }
        }
    }

    asm volatile("s_waitcnt vmcnt(0)" ::: "memory");
    __syncthreads();

    // ---- gather-FMA tap loop: one bin per lane ----
    if (lane < NBINS) {
        const float* t   = s_tile + wv * TILE_D;
        const uint2* dsc = (const uint2*)s_desc;
        const int oy = lane / 7;
        const int ox = lane - oy * 7;
        const int sbin = oy * 28 + ox * 2;   // s = (2*oy)*14 + 2*ox
        float acc = 0.0f;
#pragma unroll
        for (int sy = 0; sy < 2; ++sy) {
#pragma unroll
            for (int sx = 0; sx < 2; ++sx) {
                const uint2 dcp = dsc[sbin + sy * 14 + sx];
                const int pk  = (int)dcp.x;
                const __half2 l2 = *(const __half2*)&dcp.y;
                const float lx = __low2float(l2);
                const float ly = __high2float(l2);
                const float hx = 1.0f - lx, hy = 1.0f - ly;
                const float v  = (pk < 0) ? 0.0f : 0.25f;
                const int c00 = pk & 0x7FF;
                const int rd  = (pk >> 11) & 0x7FF;
                const int dx  = (pk >> 22) & 1;
                acc += (hy * hx * v) * t[c00]
                     + (hy * lx * v) * t[c00 + dx]
                     + (ly * hx * v) * t[c00 + rd]
                     + (ly * lx * v) * t[c00 + rd + dx];
            }
        }
        const int c = g * CPG + wv;
        out[((size_t)k * C_TOTAL + c) * NBINS + lane] = acc;
    }
}

extern "C" void kernel_launch(void* const* d_in, const int* in_sizes, int n_in,
                              void* d_out, int out_size, void* d_ws, size_t ws_size,
                              hipStream_t stream) {
    const float* f0   = (const float*)d_in[0];
    const float* f1   = (const float*)d_in[1];
    const float* f2   = (const float*)d_in[2];
    const float* f3   = (const float*)d_in[3];
    const float* rois = (const float*)d_in[4];
    float* out = (float*)d_out;
    int*   ws  = (int*)d_ws;

    const int K = in_sizes[4] / 5;
    const int blobBase = K * SD_STRIDE;
    const int kbase    = blobBase + K * BLOB_DW;
    const int sbase    = kbase + SORTN;

    roi_desc_kernel<<<K, 256, 0, stream>>>(rois, ws, blobBase, kbase);
    roi_sort_kernel<<<1, 256, 0, stream>>>(ws, K, kbase, sbase);

    dim3 grid(NGROUPS, K, 1);
    roi_align_main<<<grid, 512, 0, stream>>>(f0, f1, f2, f3, ws, out, blobBase, sbase);
}